// Round 1
// 703.033 us; speedup vs baseline: 1.1003x; 1.1003x over previous
//
#include <hip/hip_runtime.h>
#include <math.h>

#define N 16384
#define D 512
#define K 1024
#define NUM_ITERS 10
#define TEMPERATURE 0.1f
#define CONCENTRATION 0.1f
#define EPS 1e-6f

typedef unsigned short ushort_t;
typedef unsigned int uint_t;
typedef unsigned long long u64;
typedef __attribute__((ext_vector_type(4))) float floatx4;
typedef __attribute__((ext_vector_type(8))) short shortx8;

// ---------- fp16 helpers ----------
__device__ inline ushort_t f2h(float f) {
    _Float16 h = (_Float16)f;            // RNE
    return *(ushort_t*)&h;
}

__device__ inline unsigned ford(float f) {   // order-preserving float->uint
    unsigned b = __float_as_uint(f);
    return (b & 0x80000000u) ? ~b : (b | 0x80000000u);
}

__device__ inline void f4add(float4& a, const float4& b) {
    a.x += b.x; a.y += b.y; a.z += b.z; a.w += b.w;
}

__device__ inline void gld16(const void* g, void* l) {
    __builtin_amdgcn_global_load_lds(
        (const __attribute__((address_space(1))) void*)(uintptr_t)(g),
        (__attribute__((address_space(3))) void*)(uintptr_t)(l), 16, 0, 0);
}

#define WAITVM(n_lit) asm volatile("s_waitcnt vmcnt(" #n_lit ")" ::: "memory")

// ---------- cast fp32 -> fp16 (A, once) + init both best buffers ----------
__global__ void split_kernel(const float* __restrict__ x, ushort_t* __restrict__ hi,
                             u64* __restrict__ best2, int n4) {
    int i = blockIdx.x * 256 + threadIdx.x;
    if (i >= n4) return;
    float4 v = ((const float4*)x)[i];
    ushort4 hv = {f2h(v.x), f2h(v.y), f2h(v.z), f2h(v.w)};
    ((ushort4*)hi)[i] = hv;
    if (i < 2 * N) best2[i] = ~0ull;
}

// ---------- row sum-of-squares for INITIAL centroids only ----------
__global__ void rowsq_kernel(const float* __restrict__ x, float* __restrict__ out, int rows) {
    int row = blockIdx.x * 4 + (threadIdx.x >> 6);
    int lane = threadIdx.x & 63;
    if (row >= rows) return;
    const float* r = x + (size_t)row * D;
    float s = 0.f;
    for (int i = lane; i < D; i += 64) { float v = r[i]; s += v * v; }
    for (int off = 32; off > 0; off >>= 1) s += __shfl_down(s, off, 64);
    if (lane == 0) out[row] = s;
}

// ---------- MFMA assign: 256x256 tile, BK=64, 8 waves, counted-vmcnt pipeline ----
// LDS is k-half-major: per operand 4 regions of 16 KB = [buf(2)][kh(2)][row(256)][4 slots x 16B].
// Half-tile H_h (h = 4u+part; part: 0=(A,kh0) 1=(B,kh0) 2=(A,kh1) 3=(B,kh1)) is a
// linear 16 KB region -> staged by 2 global_load_lds issues of 512 lanes x 16B.
// Swizzle: logical k-chunk kb stored at slot kb ^ (row&3) ^ ((row>>2)&3)
// (bijective per row; read-side reduces to lane bits -> 2-way bank alias = free).
// Schedule: 4 phases per K-tile u (P0:kh0/i0-3, P1:kh0/i4-7, P2:kh1/i0-3, P3:kh1/i4-7),
// 16 MFMA per phase. Phase g stages H_{g+6} (prologue pre-stages H0..H5).
// Waits ONLY at ends of P1/P3: lgkmcnt(0); vmcnt(8); s_barrier  -> 4 halves
// (8 loads) stay in flight across every barrier; tail drains 8 -> 4 -> 0.
// K-accumulation order per output fragment is identical to the previous kernel
// (k = 0,32,...,480 ascending) -> bit-identical assignments.
__global__ __launch_bounds__(512, 2) void assign_mfma2(
    const ushort_t* __restrict__ Ah, const ushort_t* __restrict__ Bh,
    const float* __restrict__ csq, u64* __restrict__ best)
{
    __shared__ __align__(16) ushort_t sA[4][8192];
    __shared__ __align__(16) ushort_t sB[4][8192];

    const int tid = threadIdx.x;
    const int lane = tid & 63;
    const int wave = tid >> 6;
    const int wr = wave >> 2, wc = wave & 3;     // 2x4 wave grid, wave tile 128x64
    const int quad = lane >> 4, l16 = lane & 15;

    // XCD-chunked swizzle: each XCD owns 8 consecutive brow x all 4 bcol.
    const int bid = (int)blockIdx.x;
    const int xid = bid & 7;
    const int s = bid >> 3;                       // 0..31
    const int brow = (xid << 3) + (s >> 2);       // 0..63
    const int bcol = s & 3;                       // 0..3
    const int row0 = brow * 256, col0 = bcol * 256;

    floatx4 acc[8][4];
#pragma unroll
    for (int a = 0; a < 8; ++a)
#pragma unroll
        for (int b = 0; b < 4; ++b) acc[a][b] = (floatx4){0.f, 0.f, 0.f, 0.f};

    // fragment-read swizzled slot offset (ushorts); independent of i/j/wr/wc
    const int swz = (quad ^ (l16 & 3) ^ ((l16 >> 2) & 3)) * 8;
    const int aoff = (wr * 128 + l16) * 32 + swz;  // + (ih*4+i)*512
    const int boff = (wc * 64 + l16) * 32 + swz;   // + j*512

    auto stage = [&](int h) {
        const int u_h = h >> 2;
        const int part = h & 3;
        const int kh = part >> 1;
        const int reg = ((u_h & 1) << 1) | kh;
        const int d_off = u_h * 64 + kh * 32;
        const ushort_t* src = (part & 1) ? Bh : Ah;
        const int r0 = (part & 1) ? col0 : row0;
        ushort_t* dstreg = (part & 1) ? &sB[reg][0] : &sA[reg][0];
#pragma unroll
        for (int ii = 0; ii < 2; ++ii) {
            const int idx = ii * 512 + tid;            // 0..1023, lane-linear per wave
            const int row = idx >> 2;
            const int kb = (idx & 3) ^ (row & 3) ^ ((row >> 2) & 3);
            gld16(src + (size_t)(r0 + row) * D + d_off + kb * 8, dstreg + idx * 8);
        }
    };

    // prologue: pre-stage H0..H5, publish H0,H1
    #pragma unroll
    for (int h = 0; h < 6; ++h) stage(h);
    WAITVM(8);
    __builtin_amdgcn_s_barrier();
    __builtin_amdgcn_sched_barrier(0);

    shortx8 fb[4];
#pragma unroll
    for (int u = 0; u < 8; ++u) {
        const int rbase = (u & 1) << 1;
#pragma unroll
        for (int p = 0; p < 4; ++p) {
            const int g = u * 4 + p;
            if (g + 6 < 32) stage(g + 6);          // issue prefetch early
            const int kh = p >> 1;
            const int ih = p & 1;
            const ushort_t* Areg = &sA[rbase + kh][0];
            const ushort_t* Breg = &sB[rbase + kh][0];
            shortx8 fa[4];
            if (ih == 0) {
#pragma unroll
                for (int j = 0; j < 4; ++j) fb[j] = *(const shortx8*)&Breg[boff + j * 512];
            }
#pragma unroll
            for (int i = 0; i < 4; ++i) fa[i] = *(const shortx8*)&Areg[aoff + (ih * 4 + i) * 512];
            __builtin_amdgcn_s_setprio(1);
#pragma unroll
            for (int i = 0; i < 4; ++i)
#pragma unroll
                for (int j = 0; j < 4; ++j)
                    acc[ih * 4 + i][j] = __builtin_amdgcn_mfma_f32_16x16x32_f16(
                        fa[i], fb[j], acc[ih * 4 + i][j], 0, 0, 0);
            __builtin_amdgcn_s_setprio(0);
            if ((p == 1 || p == 3) && !(u == 7 && p == 3)) {
                asm volatile("s_waitcnt lgkmcnt(0)" ::: "memory"); // LDS reads drained
                if (u == 7 && p == 1)      { WAITVM(0); }
                else if (u == 6 && p == 3) { WAITVM(4); }
                else                       { WAITVM(8); }          // 4 halves in flight
                __builtin_amdgcn_s_barrier();
                __builtin_amdgcn_sched_barrier(0);
            }
        }
    }

    // epilogue: per-row argmin over this wave's 64 cols, then global atomicMin merge
    float csqv[4];
#pragma unroll
    for (int j = 0; j < 4; ++j) csqv[j] = csq[col0 + wc * 64 + j * 16 + l16];

    const int k0 = col0 + wc * 64 + l16;
#pragma unroll
    for (int i = 0; i < 8; ++i) {
#pragma unroll
        for (int r = 0; r < 4; ++r) {
            float bv = csqv[0] - 2.0f * acc[i][0][r];
            int bk = k0;
#pragma unroll
            for (int j = 1; j < 4; ++j) {
                float v = csqv[j] - 2.0f * acc[i][j][r];
                int kk = k0 + j * 16;
                if (v < bv || (v == bv && kk < bk)) { bv = v; bk = kk; }
            }
#pragma unroll
            for (int m = 1; m < 16; m <<= 1) {
                float ov = __shfl_xor(bv, m, 64);
                int ok = __shfl_xor(bk, m, 64);
                if (ov < bv || (ov == bv && ok < bk)) { bv = ov; bk = ok; }
            }
            if (l16 == 0) {
                int p = row0 + wr * 128 + i * 16 + quad * 4 + r;
                u64 pk = ((u64)ford(bv) << 32) | (unsigned)bk;
                atomicMin(&best[p], pk);
            }
        }
    }
}

// ======== round-based gather-then-process segment reduce ========
#define CU_WAVES 8
#define CHUNKS (N / 128)          // 128 chunks of 128 points
#define ROUNDS 4
#define WIN (CHUNKS / ROUNDS)     // 32 chunks/round
#define CPW (WIN / CU_WAVES)      // 4 chunks per wave per round

__global__ __launch_bounds__(512) void cluster_update(
    const float* __restrict__ feats, const u64* __restrict__ best,
    u64* __restrict__ best_other,
    float* __restrict__ cent, ushort_t* __restrict__ Bh,
    float* __restrict__ csq)
{
    __shared__ int list[CU_WAVES][CPW * 128];
    __shared__ int lcnt[CU_WAVES];
    __shared__ float4 part[CU_WAVES][64][2];
    __shared__ int pcnt_s[CU_WAVES];

    const int tid = threadIdx.x;
    const int lane = tid & 63;
    const int wave = tid >> 6;
    const int k = (int)blockIdx.x;

    float4 a0 = {0.f, 0.f, 0.f, 0.f}, a1 = {0.f, 0.f, 0.f, 0.f};
    int cnttot = 0;

    for (int round = 0; round < ROUNDS; ++round) {
        int cw = 0;
#pragma unroll
        for (int cc = 0; cc < CPW; ++cc) {
            int chunk = round * WIN + wave * CPW + cc;
            ulonglong2 v = ((const ulonglong2*)best)[chunk * 64 + lane];
            int id0 = (int)(uint_t)v.x;
            int id1 = (int)(uint_t)v.y;
            int p0 = chunk * 128 + 2 * lane;
            u64 m0 = __ballot(id0 == k);
            u64 m1 = __ballot(id1 == k);
            int c0 = __popcll(m0);
            u64 lanem = (1ull << lane) - 1ull;
            if (id0 == k) list[wave][cw + __popcll(m0 & lanem)] = p0;
            if (id1 == k) list[wave][cw + c0 + __popcll(m1 & lanem)] = p0 + 1;
            cw += c0 + __popcll(m1);
        }
        if (lane == 0) lcnt[wave] = cw;
        cnttot += cw;
        __syncthreads();

        int off[CU_WAVES]; int T = 0;
#pragma unroll
        for (int j = 0; j < CU_WAVES; ++j) { off[j] = T; T += lcnt[j]; }

        for (int g0 = wave; g0 < T; g0 += CU_WAVES * 4) {
            int nb = 0; int pidx[4];
#pragma unroll
            for (int b = 0; b < 4; ++b) {
                int g = g0 + CU_WAVES * b;
                if (g < T) {
                    int j = 0;
#pragma unroll
                    for (int jj = 1; jj < CU_WAVES; ++jj) if (g >= off[jj]) j = jj;
                    pidx[nb++] = list[j][g - off[j]];
                }
            }
            float4 x[4][2];
#pragma unroll
            for (int b = 0; b < 4; ++b) if (b < nb) {
                const float4* r = (const float4*)(feats + (size_t)pidx[b] * D) + lane * 2;
                x[b][0] = r[0]; x[b][1] = r[1];
            }
#pragma unroll
            for (int b = 0; b < 4; ++b) if (b < nb) {
                f4add(a0, x[b][0]); f4add(a1, x[b][1]);
            }
        }
        __syncthreads();
    }

    part[wave][lane][0] = a0; part[wave][lane][1] = a1;
    if (lane == 0) pcnt_s[wave] = cnttot;
    __syncthreads();

    if (wave == 0) {
        float4 s0 = part[0][lane][0], s1 = part[0][lane][1];
        int c = pcnt_s[0];
#pragma unroll
        for (int w = 1; w < CU_WAVES; ++w) {
            f4add(s0, part[w][lane][0]); f4add(s1, part[w][lane][1]);
            c += pcnt_s[w];
        }

        float4* crow = (float4*)(cent + (size_t)k * D) + lane * 2;
        float4 c0, c1;
        if (c > 0) {
            float cf = (float)c;
            c0 = (float4){s0.x / cf, s0.y / cf, s0.z / cf, s0.w / cf};
            c1 = (float4){s1.x / cf, s1.y / cf, s1.z / cf, s1.w / cf};
        } else {
            c0 = crow[0]; c1 = crow[1];
        }
        crow[0] = c0; crow[1] = c1;

        ushort4 hv;
        hv.x = f2h(c0.x); hv.y = f2h(c0.y); hv.z = f2h(c0.z); hv.w = f2h(c0.w);
        ((ushort4*)(Bh + (size_t)k * D))[lane * 2] = hv;
        hv.x = f2h(c1.x); hv.y = f2h(c1.y); hv.z = f2h(c1.z); hv.w = f2h(c1.w);
        ((ushort4*)(Bh + (size_t)k * D))[lane * 2 + 1] = hv;

        float s = c0.x * c0.x + c0.y * c0.y + c0.z * c0.z + c0.w * c0.w
                + c1.x * c1.x + c1.y * c1.y + c1.z * c1.z + c1.w * c1.w;
        for (int o = 32; o > 0; o >>= 1) s += __shfl_xor(s, o, 64);
        if (lane == 0) csq[k] = s;
    }

    // reset our 16-entry slice of the OTHER buffer for the next assign
    if (tid < 16) best_other[k * 16 + tid] = ~0ull;
}

// ---------- residual^2 segment sum, same scan scheme ----------
__global__ __launch_bounds__(512) void dist_gather(
    const float* __restrict__ feats, const float* __restrict__ cent,
    const u64* __restrict__ best, float* __restrict__ dists)
{
    __shared__ int list[CU_WAVES][CPW * 128];
    __shared__ int lcnt[CU_WAVES];
    __shared__ float4 part[CU_WAVES][64][2];

    const int tid = threadIdx.x;
    const int lane = tid & 63;
    const int wave = tid >> 6;
    const int k = (int)blockIdx.x;

    const float4* crow = (const float4*)(cent + (size_t)k * D) + lane * 2;
    const float4 c0 = crow[0], c1 = crow[1];

    float4 a0 = {0.f, 0.f, 0.f, 0.f}, a1 = {0.f, 0.f, 0.f, 0.f};

    for (int round = 0; round < ROUNDS; ++round) {
        int cw = 0;
#pragma unroll
        for (int cc = 0; cc < CPW; ++cc) {
            int chunk = round * WIN + wave * CPW + cc;
            ulonglong2 v = ((const ulonglong2*)best)[chunk * 64 + lane];
            int id0 = (int)(uint_t)v.x;
            int id1 = (int)(uint_t)v.y;
            int p0 = chunk * 128 + 2 * lane;
            u64 m0 = __ballot(id0 == k);
            u64 m1 = __ballot(id1 == k);
            int cc0 = __popcll(m0);
            u64 lanem = (1ull << lane) - 1ull;
            if (id0 == k) list[wave][cw + __popcll(m0 & lanem)] = p0;
            if (id1 == k) list[wave][cw + cc0 + __popcll(m1 & lanem)] = p0 + 1;
            cw += cc0 + __popcll(m1);
        }
        if (lane == 0) lcnt[wave] = cw;
        __syncthreads();

        int off[CU_WAVES]; int T = 0;
#pragma unroll
        for (int j = 0; j < CU_WAVES; ++j) { off[j] = T; T += lcnt[j]; }

        for (int g0 = wave; g0 < T; g0 += CU_WAVES * 4) {
            int nb = 0; int pidx[4];
#pragma unroll
            for (int b = 0; b < 4; ++b) {
                int g = g0 + CU_WAVES * b;
                if (g < T) {
                    int j = 0;
#pragma unroll
                    for (int jj = 1; jj < CU_WAVES; ++jj) if (g >= off[jj]) j = jj;
                    pidx[nb++] = list[j][g - off[j]];
                }
            }
            float4 x[4][2];
#pragma unroll
            for (int b = 0; b < 4; ++b) if (b < nb) {
                const float4* r = (const float4*)(feats + (size_t)pidx[b] * D) + lane * 2;
                x[b][0] = r[0]; x[b][1] = r[1];
            }
#pragma unroll
            for (int b = 0; b < 4; ++b) if (b < nb) {
                float r;
                r = x[b][0].x - c0.x; a0.x += r * r;  r = x[b][0].y - c0.y; a0.y += r * r;
                r = x[b][0].z - c0.z; a0.z += r * r;  r = x[b][0].w - c0.w; a0.w += r * r;
                r = x[b][1].x - c1.x; a1.x += r * r;  r = x[b][1].y - c1.y; a1.y += r * r;
                r = x[b][1].z - c1.z; a1.z += r * r;  r = x[b][1].w - c1.w; a1.w += r * r;
            }
        }
        __syncthreads();
    }

    part[wave][lane][0] = a0; part[wave][lane][1] = a1;
    __syncthreads();
    if (wave == 0) {
        float4 s0 = part[0][lane][0], s1 = part[0][lane][1];
#pragma unroll
        for (int w = 1; w < CU_WAVES; ++w) { f4add(s0, part[w][lane][0]); f4add(s1, part[w][lane][1]); }
        float4* drow = (float4*)(dists + (size_t)k * D) + lane * 2;
        drow[0] = s0; drow[1] = s1;
    }
}

// ---------- loss (grid-stride, 256 blocks -> 256 atomics not 2048) ----------
__global__ void sump_kernel(const float* __restrict__ dists, double* __restrict__ S) {
    int tid = threadIdx.x;
    float v = 0.f;
    for (int idx = blockIdx.x * 256 + tid; idx < K * D; idx += 256 * 256)
        v += expf(-(dists[idx] / CONCENTRATION));
    __shared__ float red[4];
    for (int off = 32; off > 0; off >>= 1) v += __shfl_down(v, off, 64);
    if ((tid & 63) == 0) red[tid >> 6] = v;
    __syncthreads();
    if (tid == 0) atomicAdd(S, (double)(red[0] + red[1] + red[2] + red[3]));
}

__global__ void loss_kernel(const float* __restrict__ dists, const double* __restrict__ Sd,
                            double* __restrict__ acc2) {
    int tid = threadIdx.x;
    float S = (float)Sd[0];
    float e = 0.f, nl = 0.f;
    for (int idx = blockIdx.x * 256 + tid; idx < K * D; idx += 256 * 256) {
        float dv = dists[idx];
        float p = expf(-(dv / CONCENTRATION));
        float qq = p / S;
        e += qq * logf(qq + EPS);
        float p2 = expf(-(dv / TEMPERATURE));
        nl += logf(p2 + EPS);
    }
    __shared__ float rede[4];
    __shared__ float redn[4];
    for (int off = 32; off > 0; off >>= 1) { e += __shfl_down(e, off, 64); nl += __shfl_down(nl, off, 64); }
    if ((tid & 63) == 0) { rede[tid >> 6] = e; redn[tid >> 6] = nl; }
    __syncthreads();
    if (tid == 0) {
        atomicAdd(&acc2[0], (double)(rede[0] + rede[1] + rede[2] + rede[3]));
        atomicAdd(&acc2[1], (double)(redn[0] + redn[1] + redn[2] + redn[3]));
    }
}

__global__ void finalize_kernel(const double* __restrict__ acc2, float* __restrict__ out) {
    double kd = (double)(K * D);
    double entropy = acc2[0] / kd;
    double nll = -(acc2[1] / kd);
    out[0] = (float)(entropy + nll);
}

extern "C" void kernel_launch(void* const* d_in, const int* in_sizes, int n_in,
                              void* d_out, int out_size, void* d_ws, size_t ws_size,
                              hipStream_t stream) {
    const float* feats = (const float*)d_in[0];
    float* out = (float*)d_out;

    ushort_t* Ah = (ushort_t*)d_ws;                  // N*D
    ushort_t* Bh = Ah + (size_t)N * D;               // K*D
    float* centroids = (float*)(Bh + (size_t)K * D); // K*D
    float* dists     = centroids + (size_t)K * D;    // K*D
    float* csq       = dists + (size_t)K * D;        // K
    u64*   best0     = (u64*)(csq + K);              // N  (contiguous with best1)
    u64*   best1     = best0 + N;                    // N
    double* scal     = (double*)(best1 + N);         // 3

    split_kernel<<<(N * D / 4) / 256, 256, 0, stream>>>(feats, Ah, best0, N * D / 4);
    hipMemcpyAsync(centroids, feats, (size_t)K * D * sizeof(float),
                   hipMemcpyDeviceToDevice, stream);
    rowsq_kernel<<<K / 4, 256, 0, stream>>>(feats, csq, K);

    for (int it = 0; it < NUM_ITERS; ++it) {
        u64* cur = (it & 1) ? best1 : best0;
        u64* oth = (it & 1) ? best0 : best1;
        const ushort_t* bh = (it == 0) ? Ah : Bh;   // iter0: init centroids = feats[:K]
        assign_mfma2<<<(N / 256) * (K / 256), 512, 0, stream>>>(Ah, bh, csq, cur);
        cluster_update<<<K, 512, 0, stream>>>(feats, cur, oth, centroids, Bh, csq);
    }
    u64* fin = (NUM_ITERS & 1) ? best1 : best0;   // reset by last cluster_update
    assign_mfma2<<<(N / 256) * (K / 256), 512, 0, stream>>>(Ah, Bh, csq, fin);

    dist_gather<<<K, 512, 0, stream>>>(feats, centroids, fin, dists);

    hipMemsetAsync(scal, 0, 3 * sizeof(double), stream);
    sump_kernel<<<256, 256, 0, stream>>>(dists, &scal[0]);
    loss_kernel<<<256, 256, 0, stream>>>(dists, &scal[0], &scal[1]);
    finalize_kernel<<<1, 1, 0, stream>>>(&scal[1], out);
}